// Round 3
// baseline (932.598 us; speedup 1.0000x reference)
//
#include <hip/hip_runtime.h>

#define BATCH 32
#define TIME  512
#define INF   512
#define HIDF  1024

#define MBT  128           // block tile: bt rows
#define NBH  256           // block tile: h cols
#define KCH  16            // k per chunk
#define NCH  (INF / KCH)   // 32 chunks
#define TILEX (MBT * KCH)  // 2048 floats = 8 KB per x buffer
#define TILEW (NBH * KCH)  // 4096 floats = 16 KB per W buffer

// async global->LDS DMA, 16 B per lane, dst = wave-uniform base + lane*16
#define GLD16(g, l) __builtin_amdgcn_global_load_lds(                      \
    (const __attribute__((address_space(1))) void*)(g),                    \
    (__attribute__((address_space(3))) void*)(l), 16, 0, 0)

// ---------------------------------------------------------------------------
// Phase 1: hidden[bt][h] = (sum_k x[bt,k]*W[h,k]) + bias[h], bit-exact vs the
// XLA canonical order: ONE fp32 accumulator per output, fused FMA, k strictly
// ascending, ONE fp32 rounding for +bias.
//
// R10: R9's 8x16 tile was right (LDS reads/FMA -25%) but the allocator
// targeted 4 waves/EU, clamped VGPR to 128 and spilled ~130 MB/dispatch to
// scratch (WRITE_SIZE 65->193 MB, dur 247->305). Fix: amdgpu_waves_per_eu(2,2)
// pins 2 waves/EU -> full 256-VGPR budget, no spill incentive; W-fragment
// loads sequenced (wf -> FMA acc0 -> reload wf -> FMA acc1) so peak live
// set ~200. Occupancy unchanged vs R8 (8 waves/CU, 2 blocks).
// ---------------------------------------------------------------------------

#define FMA_COMP(acc, xf, wf, COMP)                                        \
    _Pragma("unroll")                                                      \
    for (int r = 0; r < 8; ++r)                                            \
        _Pragma("unroll")                                                  \
        for (int c = 0; c < 8; ++c)                                        \
            acc[r][c] = __fmaf_rn(xf[r].COMP, wf[c].COMP, acc[r][c]);

#define FMA_GROUP(acc, xf, wf)                                             \
    FMA_COMP(acc, xf, wf, x)                                               \
    FMA_COMP(acc, xf, wf, y)                                               \
    FMA_COMP(acc, xf, wf, z)                                               \
    FMA_COMP(acc, xf, wf, w)

__global__ __launch_bounds__(256)
__attribute__((amdgpu_waves_per_eu(2, 2)))
void snn_gemm_seqfma(const float* __restrict__ x, const float* __restrict__ W,
                     const float* __restrict__ bias, float* __restrict__ hidden) {
    __shared__ __align__(16) float xs[2 * TILEX];   // 16 KB
    __shared__ __align__(16) float ws[2 * TILEW];   // 32 KB

    const int tid = threadIdx.x;
    const int l   = tid & 63;
    const int wv  = __builtin_amdgcn_readfirstlane(tid >> 6);  // wave 0..3
    const int lx  = l & 7;           // h octet within wave sub-tile
    const int ly  = (l >> 3) & 7;    // bt octet within wave sub-tile
    const int bt0 = blockIdx.y * MBT;
    const int h0  = blockIdx.x * NBH;
    // wave sub-tile origin inside the 128x256 block tile
    const int wbt = 64 * (wv >> 1);   // bt offset: 0 or 64
    const int whh = 128 * (wv & 1);   // h  offset: 0 or 128

    // ---- DMA staging ----
    // x: 128 rows, wave wv stages rows 32wv..32wv+31 (2 GLD16/thread)
    // W: 256 rows, wave wv stages rows 64wv..64wv+63 (4 GLD16/thread)
    const int rl = l >> 2;
    const int qs = l & 3;
    const int rxA = 32 * wv + rl;
    const int rxB = rxA + 16;
    const int rw0 = 64 * wv + rl;
    const int rw1 = rw0 + 16;
    const int rw2 = rw0 + 32;
    const int rw3 = rw0 + 48;
    const float* xgA = x + (size_t)(bt0 + rxA) * INF + (qs ^ ((rxA >> 3) & 3)) * 4;
    const float* xgB = x + (size_t)(bt0 + rxB) * INF + (qs ^ ((rxB >> 3) & 3)) * 4;
    const float* wg0 = W + (size_t)(h0 + rw0) * INF + (qs ^ ((rw0 >> 3) & 3)) * 4;
    const float* wg1 = W + (size_t)(h0 + rw1) * INF + (qs ^ ((rw1 >> 3) & 3)) * 4;
    const float* wg2 = W + (size_t)(h0 + rw2) * INF + (qs ^ ((rw2 >> 3) & 3)) * 4;
    const float* wg3 = W + (size_t)(h0 + rw3) * INF + (qs ^ ((rw3 >> 3) & 3)) * 4;
    const int dXA = (32 * wv) * KCH;        // wave-uniform LDS float offsets
    const int dXB = dXA + 16 * KCH;
    const int dW0 = (64 * wv) * KCH;
    const int dW1 = dW0 + 16 * KCH;
    const int dW2 = dW0 + 32 * KCH;
    const int dW3 = dW0 + 48 * KCH;

    // ---- prologue: stage chunk 0 into buffer 0 ----
    GLD16(xgA, xs + dXA);
    GLD16(xgB, xs + dXB);
    GLD16(wg0, ws + dW0);
    GLD16(wg1, ws + dW1);
    GLD16(wg2, ws + dW2);
    GLD16(wg3, ws + dW3);

    float acc0[8][8], acc1[8][8];
    #pragma unroll
    for (int r = 0; r < 8; ++r)
        #pragma unroll
        for (int c = 0; c < 8; ++c) { acc0[r][c] = 0.0f; acc1[r][c] = 0.0f; }

    __syncthreads();   // drains vmcnt -> chunk 0 resident

    for (int kc = 0; kc < NCH; ++kc) {
        const int p  = kc & 1;
        const int np = p ^ 1;

        // ---- issue next chunk's DMAs into the other buffer (async) ----
        if (kc + 1 < NCH) {
            const int so = (kc + 1) * KCH;    // float offset within a row
            float* xd = xs + np * TILEX;
            float* wd = ws + np * TILEW;
            GLD16(xgA + so, xd + dXA);
            GLD16(xgB + so, xd + dXB);
            GLD16(wg0 + so, wd + dW0);
            GLD16(wg1 + so, wd + dW1);
            GLD16(wg2 + so, wd + dW2);
            GLD16(wg3 + so, wd + dW3);
        }

        // ---- compute on current buffer: 4 groups of 4 k, g ascending ----
        const float* xb = xs + p * TILEX;
        const float* wb = ws + p * TILEW;
        #pragma unroll
        for (int g = 0; g < 4; ++g) {
            const int gx_ = (g ^ (ly & 3)) * 4;   // storage quad for x rows
            const int gw_ = (g ^ (lx & 3)) * 4;   // storage quad for W rows
            // (+64-row half uses the SAME storage quad: (64>>3)&3 == 0)
            const float* xr = xb + (wbt + ly * 8) * KCH + gx_;
            const float* wr = wb + (whh + lx * 8) * KCH + gw_;
            float4 xf[8], wf[8];
            #pragma unroll
            for (int r = 0; r < 8; ++r)
                xf[r] = *(const float4*)(xr + r * KCH);
            #pragma unroll
            for (int c = 0; c < 8; ++c)
                wf[c] = *(const float4*)(wr + c * KCH);
            // k strictly ascending within the group for every chain
            FMA_GROUP(acc0, xf, wf)
            #pragma unroll
            for (int c = 0; c < 8; ++c)
                wf[c] = *(const float4*)(wr + 64 * KCH + c * KCH);
            FMA_GROUP(acc1, xf, wf)
        }
        __syncthreads();   // all waves done with buf p; buf np's DMAs drained
    }

    // ---- epilogue: one fp32 rounding for bias, float4 stores ----
    float bv0[8], bv1[8];
    #pragma unroll
    for (int c = 0; c < 8; ++c) {
        bv0[c] = bias[h0 + whh + lx * 8 + c];
        bv1[c] = bias[h0 + whh + 64 + lx * 8 + c];
    }
    #pragma unroll
    for (int r = 0; r < 8; ++r) {
        float* orow = hidden + (size_t)(bt0 + wbt + ly * 8 + r) * HIDF
                             + h0 + whh + lx * 8;
        float4 o0, o1, o2, o3;
        o0.x = __fadd_rn(acc0[r][0], bv0[0]);
        o0.y = __fadd_rn(acc0[r][1], bv0[1]);
        o0.z = __fadd_rn(acc0[r][2], bv0[2]);
        o0.w = __fadd_rn(acc0[r][3], bv0[3]);
        o1.x = __fadd_rn(acc0[r][4], bv0[4]);
        o1.y = __fadd_rn(acc0[r][5], bv0[5]);
        o1.z = __fadd_rn(acc0[r][6], bv0[6]);
        o1.w = __fadd_rn(acc0[r][7], bv0[7]);
        o2.x = __fadd_rn(acc1[r][0], bv1[0]);
        o2.y = __fadd_rn(acc1[r][1], bv1[1]);
        o2.z = __fadd_rn(acc1[r][2], bv1[2]);
        o2.w = __fadd_rn(acc1[r][3], bv1[3]);
        o3.x = __fadd_rn(acc1[r][4], bv1[4]);
        o3.y = __fadd_rn(acc1[r][5], bv1[5]);
        o3.z = __fadd_rn(acc1[r][6], bv1[6]);
        o3.w = __fadd_rn(acc1[r][7], bv1[7]);
        ((float4*)orow)[0]  = o0;
        ((float4*)orow)[1]  = o1;
        ((float4*)(orow + 64))[0] = o2;
        ((float4*)(orow + 64))[1] = o3;
    }
}

// ---------------------------------------------------------------------------
// Phase 2: in-place LIF scan over t per (b,h) column, fp32:
//   mem = fl32(0.5*mem + h_t); spk = mem > 1.0f; hard reset to 0.
// Residual (total - gemm) is harness overhead + ~15-20 us scan; left as-is.
// ---------------------------------------------------------------------------
#define SEG 32

__global__ __launch_bounds__(64)
void snn_scan_np(float* __restrict__ io) {
    const int n = blockIdx.x * 64 + threadIdx.x;   // 0..32767
    const int b = n >> 10;
    const int h = n & 1023;
    float* p = io + (size_t)b * TIME * HIDF + h;

    float A[SEG], B[SEG];
    float mem = 0.0f;

    #pragma unroll
    for (int u = 0; u < SEG; ++u) A[u] = p[u * HIDF];

    for (int tb = 0; tb < TIME / SEG; tb += 2) {
        #pragma unroll
        for (int u = 0; u < SEG; ++u) B[u] = p[((tb + 1) * SEG + u) * HIDF];
        #pragma unroll
        for (int u = 0; u < SEG; ++u) {
            mem = __fadd_rn(__fmul_rn(0.5f, mem), A[u]);
            const bool s = mem > 1.0f;
            p[(tb * SEG + u) * HIDF] = s ? 1.0f : 0.0f;
            if (s) mem = 0.0f;
        }
        if (tb + 2 < TIME / SEG) {
            #pragma unroll
            for (int u = 0; u < SEG; ++u) A[u] = p[((tb + 2) * SEG + u) * HIDF];
        }
        #pragma unroll
        for (int u = 0; u < SEG; ++u) {
            mem = __fadd_rn(__fmul_rn(0.5f, mem), B[u]);
            const bool s = mem > 1.0f;
            p[((tb + 1) * SEG + u) * HIDF] = s ? 1.0f : 0.0f;
            if (s) mem = 0.0f;
        }
    }
}

extern "C" void kernel_launch(void* const* d_in, const int* in_sizes, int n_in,
                              void* d_out, int out_size, void* d_ws, size_t ws_size,
                              hipStream_t stream) {
    const float* x    = (const float*)d_in[0];   // [32, 512, 512]
    const float* W    = (const float*)d_in[1];   // [1024, 512]
    const float* bias = (const float*)d_in[2];   // [1024]
    float* out = (float*)d_out;                  // [32, 512, 1024]

    dim3 g1(HIDF / NBH, (BATCH * TIME) / MBT);   // (4, 128) = 512 blocks
    snn_gemm_seqfma<<<g1, 256, 0, stream>>>(x, W, bias, out);

    snn_scan_np<<<(BATCH * HIDF) / 64, 64, 0, stream>>>(out);
}

// Round 4
// 314.350 us; speedup vs baseline: 2.9668x; 2.9668x over previous
//
#include <hip/hip_runtime.h>

#define BATCH 32
#define TIME  512
#define INF   512
#define HIDF  1024

#define MBT  128          // block tile: bt rows
#define NBH  128          // block tile: h cols
#define KCH  16           // k per chunk
#define NCH  (INF / KCH)  // 32 chunks
#define TILEF (MBT * KCH) // 2048 floats = 8 KB per buffer

// async global->LDS DMA, 16 B per lane, dst = wave-uniform base + lane*16
#define GLD16(g, l) __builtin_amdgcn_global_load_lds(                      \
    (const __attribute__((address_space(1))) void*)(g),                    \
    (__attribute__((address_space(3))) void*)(l), 16, 0, 0)

// ---------------------------------------------------------------------------
// Phase 1: hidden[bt][h] = (sum_k x[bt,k]*W[h,k]) + bias[h], bit-exact vs the
// XLA canonical order: ONE fp32 accumulator per output, fused FMA, k strictly
// ascending, ONE fp32 rounding for +bias.
//
// R11 (revert R9/R10 tile experiments: allocator is hard-capped at 128 VGPR,
// spills killed both; back to R8's 8x8 lane tile, VGPR 88, then fix the
// measured 2.0 conflict-cyc/ds_read):
//
// Conflict-free LDS scheme. A wave b128 read has 8 broadcast addresses (one
// per lane octet). Old layout: row stride 8 between octets -> constant row
// parity -> only 4 bank-quads -> 2-way conflict on EVERY read (1.678e7 cyc).
// New: within each 16-row window, global row 8*(s&1)+(s>>1) is staged into
// slot s (realized purely by permuting the per-lane GLOBAL source address of
// GLD16 - LDS dst stays linear), plus quad-XOR by (window&3). Octet ly then
// reads slots (ly&1)+2r of window (ly>>1): bank group
// (ly&1)*16 + (g^(ly>>1))*4 -> 8 distinct quads, all 32 banks exactly once.
// The permutation composes so lane ly still gets exactly global rows
// wbt+8*ly+r with k-quads in ascending order: stores + FMA order unchanged.
// ---------------------------------------------------------------------------
__global__ __launch_bounds__(256, 2)
void snn_gemm_seqfma(const float* __restrict__ x, const float* __restrict__ W,
                     const float* __restrict__ bias, float* __restrict__ hidden) {
    __shared__ __align__(16) float xs[2 * TILEF];   // 16 KB
    __shared__ __align__(16) float ws[2 * TILEF];   // 16 KB

    const int tid = threadIdx.x;
    const int l   = tid & 63;
    const int wv  = __builtin_amdgcn_readfirstlane(tid >> 6);  // wave 0..3
    const int lx  = l & 7;           // h octet within wave sub-tile
    const int ly  = (l >> 3) & 7;    // bt octet within wave sub-tile
    const int bt0 = blockIdx.y * MBT;
    const int h0  = blockIdx.x * NBH;
    // wave sub-tile origin inside the 128x128 block tile
    const int wbt = 64 * (wv >> 1);  // bt offset: 0 or 64
    const int wh  = 64 * (wv & 1);   // h  offset: 0 or 64

    // ---- DMA staging: wave wv stages windows 2wv, 2wv+1 (16 rows each) ----
    // slot s in a window holds global row offset 8*(s&1) + (s>>1); quad
    // position q holds data quad q ^ (window&3).
    const int rl = l >> 2;                        // slot within window, 0..15
    const int qs = l & 3;                         // quad position, 0..3
    const int g0 = ((rl & 1) << 3) | (rl >> 1);   // global row offset for slot
    const int wA = 2 * wv;                        // window indices
    const int wB = 2 * wv + 1;
    const int rA = wA * 16 + g0;                  // global row (block-rel)
    const int rB = wB * 16 + g0;
    const int qA = qs ^ (wA & 3);
    const int qB = qs ^ (wB & 3);
    const float* xgA = x + (size_t)(bt0 + rA) * INF + qA * 4;
    const float* xgB = x + (size_t)(bt0 + rB) * INF + qB * 4;
    const float* wgA = W + (size_t)(h0 + rA) * INF + qA * 4;
    const float* wgB = W + (size_t)(h0 + rB) * INF + qB * 4;
    const int dOffA = (32 * wv) * KCH;        // wave-uniform LDS float offset
    const int dOffB = dOffA + 16 * KCH;

    // ---- prologue: stage chunk 0 into buffer 0 ----
    GLD16(xgA, xs + dOffA);
    GLD16(xgB, xs + dOffB);
    GLD16(wgA, ws + dOffA);
    GLD16(wgB, ws + dOffB);

    float acc[8][8];
    #pragma unroll
    for (int r = 0; r < 8; ++r)
        #pragma unroll
        for (int c = 0; c < 8; ++c) acc[r][c] = 0.0f;

    __syncthreads();   // drains vmcnt -> chunk 0 resident

    // per-lane read bases: octet o reads slots (o&1) + 2*idx of window (o>>1)
    const int xrow0 = wbt + (ly >> 1) * 16 + (ly & 1);
    const int wrow0 = wh  + (lx >> 1) * 16 + (lx & 1);
    const int xq = (ly >> 1) & 3;    // quad-XOR seen by this lane's x rows
    const int wq = (lx >> 1) & 3;    // quad-XOR seen by this lane's W rows

    for (int kc = 0; kc < NCH; ++kc) {
        const int p  = kc & 1;
        const int np = p ^ 1;

        // ---- issue next chunk's DMAs into the other buffer (async) ----
        if (kc + 1 < NCH) {
            const int so = (kc + 1) * KCH;    // float offset within a row
            float* xd = xs + np * TILEF;
            float* wd = ws + np * TILEF;
            GLD16(xgA + so, xd + dOffA);
            GLD16(xgB + so, xd + dOffB);
            GLD16(wgA + so, wd + dOffA);
            GLD16(wgB + so, wd + dOffB);
        }

        // ---- compute on current buffer: 4 groups of 4 k, g ascending ----
        const float* xb = xs + p * TILEF;
        const float* wb = ws + p * TILEF;
        #pragma unroll
        for (int g = 0; g < 4; ++g) {
            const int gx_ = (g ^ xq) * 4;     // storage quad for x rows
            const int gw_ = (g ^ wq) * 4;     // storage quad for W rows
            const float* xr = xb + xrow0 * KCH + gx_;
            const float* wr = wb + wrow0 * KCH + gw_;
            float4 xf[8], wf[8];
            #pragma unroll
            for (int r = 0; r < 8; ++r)
                xf[r] = *(const float4*)(xr + r * 2 * KCH);   // slot +2 rows
            #pragma unroll
            for (int c = 0; c < 8; ++c)
                wf[c] = *(const float4*)(wr + c * 2 * KCH);
            // xf[r] = data quads g of global row wbt+8ly+r (k ascending);
            // k strictly ascending within the group for every (r,c) chain
            #pragma unroll
            for (int r = 0; r < 8; ++r)
                #pragma unroll
                for (int c = 0; c < 8; ++c)
                    acc[r][c] = __fmaf_rn(xf[r].x, wf[c].x, acc[r][c]);
            #pragma unroll
            for (int r = 0; r < 8; ++r)
                #pragma unroll
                for (int c = 0; c < 8; ++c)
                    acc[r][c] = __fmaf_rn(xf[r].y, wf[c].y, acc[r][c]);
            #pragma unroll
            for (int r = 0; r < 8; ++r)
                #pragma unroll
                for (int c = 0; c < 8; ++c)
                    acc[r][c] = __fmaf_rn(xf[r].z, wf[c].z, acc[r][c]);
            #pragma unroll
            for (int r = 0; r < 8; ++r)
                #pragma unroll
                for (int c = 0; c < 8; ++c)
                    acc[r][c] = __fmaf_rn(xf[r].w, wf[c].w, acc[r][c]);
        }
        __syncthreads();   // all waves done with buf p; buf np's DMAs drained
    }

    // ---- epilogue: one fp32 rounding for bias, float4 stores (as R8) ----
    float bv[8];
    #pragma unroll
    for (int c = 0; c < 8; ++c) bv[c] = bias[h0 + wh + lx * 8 + c];
    #pragma unroll
    for (int r = 0; r < 8; ++r) {
        float* orow = hidden + (size_t)(bt0 + wbt + ly * 8 + r) * HIDF
                             + h0 + wh + lx * 8;
        float4 o0, o1;
        o0.x = __fadd_rn(acc[r][0], bv[0]);
        o0.y = __fadd_rn(acc[r][1], bv[1]);
        o0.z = __fadd_rn(acc[r][2], bv[2]);
        o0.w = __fadd_rn(acc[r][3], bv[3]);
        o1.x = __fadd_rn(acc[r][4], bv[4]);
        o1.y = __fadd_rn(acc[r][5], bv[5]);
        o1.z = __fadd_rn(acc[r][6], bv[6]);
        o1.w = __fadd_rn(acc[r][7], bv[7]);
        ((float4*)orow)[0] = o0;
        ((float4*)orow)[1] = o1;
    }
}

// ---------------------------------------------------------------------------
// Phase 2: in-place LIF scan over t per (b,h) column, fp32:
//   mem = fl32(0.5*mem + h_t); spk = mem > 1.0f; hard reset to 0.
// Residual (total - gemm) is harness overhead + ~15-20 us scan; left as-is.
// ---------------------------------------------------------------------------
#define SEG 32

__global__ __launch_bounds__(64)
void snn_scan_np(float* __restrict__ io) {
    const int n = blockIdx.x * 64 + threadIdx.x;   // 0..32767
    const int b = n >> 10;
    const int h = n & 1023;
    float* p = io + (size_t)b * TIME * HIDF + h;

    float A[SEG], B[SEG];
    float mem = 0.0f;

    #pragma unroll
    for (int u = 0; u < SEG; ++u) A[u] = p[u * HIDF];

    for (int tb = 0; tb < TIME / SEG; tb += 2) {
        #pragma unroll
        for (int u = 0; u < SEG; ++u) B[u] = p[((tb + 1) * SEG + u) * HIDF];
        #pragma unroll
        for (int u = 0; u < SEG; ++u) {
            mem = __fadd_rn(__fmul_rn(0.5f, mem), A[u]);
            const bool s = mem > 1.0f;
            p[(tb * SEG + u) * HIDF] = s ? 1.0f : 0.0f;
            if (s) mem = 0.0f;
        }
        if (tb + 2 < TIME / SEG) {
            #pragma unroll
            for (int u = 0; u < SEG; ++u) A[u] = p[((tb + 2) * SEG + u) * HIDF];
        }
        #pragma unroll
        for (int u = 0; u < SEG; ++u) {
            mem = __fadd_rn(__fmul_rn(0.5f, mem), B[u]);
            const bool s = mem > 1.0f;
            p[((tb + 1) * SEG + u) * HIDF] = s ? 1.0f : 0.0f;
            if (s) mem = 0.0f;
        }
    }
}

extern "C" void kernel_launch(void* const* d_in, const int* in_sizes, int n_in,
                              void* d_out, int out_size, void* d_ws, size_t ws_size,
                              hipStream_t stream) {
    const float* x    = (const float*)d_in[0];   // [32, 512, 512]
    const float* W    = (const float*)d_in[1];   // [1024, 512]
    const float* bias = (const float*)d_in[2];   // [1024]
    float* out = (float*)d_out;                  // [32, 512, 1024]

    dim3 g1(HIDF / NBH, (BATCH * TIME) / MBT);   // (8, 128) = 1024 blocks
    snn_gemm_seqfma<<<g1, 256, 0, stream>>>(x, W, bias, out);

    snn_scan_np<<<(BATCH * HIDF) / 64, 64, 0, stream>>>(out);
}